// Round 7
// baseline (160.909 us; speedup 1.0000x reference)
//
#include <hip/hip_runtime.h>
#include <hip/hip_bf16.h>

#define N_NODES 100000
#define N_EDGES 500000

using bf16x8 = __attribute__((ext_vector_type(8))) __bf16;
using f32x4  = __attribute__((ext_vector_type(4))) float;

// ws layout: [0,64KB) w1f = W' [128,256] bf16, MFMA B-fragment order;
//            [64KB, +51.2MB) C = [N_NODES][256] bf16, PERMUTED per 128-col half:
//            C[r][h*128 + (c&15)*8 + (c>>4)] = (z[r] @ W'_h)[c]
// h = relu(src@W1a + dst@W1b + b1); W' = [W1a | W1b]

// ---- kernel 1: W1 f32 -> W' bf16 fragment-ordered ----
// frag = kq*16 + c16 ; lane holds W'[k = kq*32+(l>>4)*8+i][n = c16*16+(l&15)]
__global__ void cvt_w1f_kernel(const float* __restrict__ W1, __bf16* __restrict__ w1f) {
    int t = blockIdx.x * 256 + threadIdx.x;  // 0..4095
    int lane = t & 63, frag = t >> 6;
    int kq = frag >> 4, c16 = frag & 15;
    int k0 = kq * 32 + (lane >> 4) * 8;
    int n  = c16 * 16 + (lane & 15);
    bf16x8 o;
#pragma unroll
    for (int i = 0; i < 8; i++) {
        int k = k0 + i;
        float w = (n < 128) ? W1[k * 128 + n] : W1[(k + 128) * 128 + (n - 128)];
        o[i] = (__bf16)w;
    }
    ((bf16x8*)w1f)[t] = o;
}

// ---- kernel 2: node GEMM, block = 256 rows x 256 cols, NO LDS ----
// z read ONCE: A-frags held bf16 in regs across both col-halves.
// B-frags loaded from L2-hot w1f (64 KB) per kq. No barrier.
__global__ __launch_bounds__(256, 2) void node_gemm_kernel(
    const float* __restrict__ z, const __bf16* __restrict__ w1f,
    __bf16* __restrict__ C)
{
    const int lane = threadIdx.x & 63;
    const int wave = threadIdx.x >> 6;
    const int l15 = lane & 15, l4 = lane >> 4;
    const int rowbase = blockIdx.x * 256 + wave * 64;

    // ---- load + convert A: 16 frags (mt x kq), 64 VGPRs as bf16 ----
    bf16x8 afr[4][4];
#pragma unroll
    for (int mt = 0; mt < 4; mt++) {
        int r = rowbase + mt * 16 + l15;
        if (r >= N_NODES) r = N_NODES - 1;        // tail clamp, store predicated
        const float* arow = z + (size_t)r * 128 + l4 * 8;
#pragma unroll
        for (int kq = 0; kq < 4; kq++) {
            const float4* p = (const float4*)(arow + kq * 32);
            float4 x0 = p[0], x1 = p[1];
            bf16x8 a;
            a[0] = (__bf16)x0.x; a[1] = (__bf16)x0.y; a[2] = (__bf16)x0.z; a[3] = (__bf16)x0.w;
            a[4] = (__bf16)x1.x; a[5] = (__bf16)x1.y; a[6] = (__bf16)x1.z; a[7] = (__bf16)x1.w;
            afr[mt][kq] = a;
        }
    }

    const f32x4 zero = {0.f, 0.f, 0.f, 0.f};

#pragma unroll
    for (int h = 0; h < 2; h++) {
        f32x4 acc[4][8];
#pragma unroll
        for (int mt = 0; mt < 4; mt++)
#pragma unroll
            for (int nt = 0; nt < 8; nt++) acc[mt][nt] = zero;

#pragma unroll
        for (int kq = 0; kq < 4; kq++) {
            bf16x8 bfr[8];
#pragma unroll
            for (int nt = 0; nt < 8; nt++)
                bfr[nt] = *(const bf16x8*)(w1f + ((kq * 16 + h * 8 + nt) * 64 + lane) * 8);
#pragma unroll
            for (int mt = 0; mt < 4; mt++)
#pragma unroll
                for (int nt = 0; nt < 8; nt++)
                    acc[mt][nt] = __builtin_amdgcn_mfma_f32_16x16x32_bf16(afr[mt][kq], bfr[nt], acc[mt][nt], 0, 0, 0);
        }

        // permuted store: C[r*256 + h*128 + l15*8 + nt] = acc[mt][nt][j]
#pragma unroll
        for (int mt = 0; mt < 4; mt++) {
#pragma unroll
            for (int j = 0; j < 4; j++) {
                int r = rowbase + mt * 16 + l4 * 4 + j;
                if (r < N_NODES) {
                    bf16x8 o;
#pragma unroll
                    for (int nt = 0; nt < 8; nt++) o[nt] = (__bf16)acc[mt][nt][j];
                    *(bf16x8*)(C + (size_t)r * 256 + h * 128 + l15 * 8) = o;
                }
            }
        }
    }
}

// ---- kernel 3: edge gather + fused epilogue (permuted-channel aware) ----
// lane = g*16 + sub ; 8 quads = 32 edges per wave-iter (16 gathers in flight)
__global__ __launch_bounds__(256, 4) void edge_kernel(
    const __bf16* __restrict__ C, const int* __restrict__ ei,
    const float* __restrict__ b1, const float* __restrict__ W2,
    const float* __restrict__ b2, float* __restrict__ out)
{
    const int lane = threadIdx.x & 63;
    const int wave = threadIdx.x >> 6;
    const int g = lane >> 4, sub = lane & 15;

    float b1v[8], w2v[8];
#pragma unroll
    for (int i = 0; i < 8; i++) {
        b1v[i] = b1[i * 16 + sub];
        w2v[i] = W2[i * 16 + sub];
    }
    const float bias2 = b2[0];

    const int wid = blockIdx.x * 4 + wave;
    const int nw  = gridDim.x * 4;

    // 32 edges per wave-iteration (8 quads); N_EDGES % 32 == 0
    for (int eb = wid * 32; eb < N_EDGES; eb += nw * 32) {
        bf16x8 cu[8], cv[8];
        int e[8];
#pragma unroll
        for (int q = 0; q < 8; q++) {
            e[q] = eb + q * 4 + g;
            int is = ei[e[q]];
            int id = ei[N_EDGES + e[q]];
            cu[q] = *(const bf16x8*)(C + (size_t)is * 256 + sub * 8);
            cv[q] = *(const bf16x8*)(C + (size_t)id * 256 + 128 + sub * 8);
        }
#pragma unroll
        for (int q = 0; q < 8; q++) {
            float p = 0.f;
#pragma unroll
            for (int i = 0; i < 8; i++) {
                float hc = (float)cu[q][i] + (float)cv[q][i] + b1v[i];
                p += fmaxf(hc, 0.f) * w2v[i];
            }
            p += __shfl_xor(p, 1, 64);
            p += __shfl_xor(p, 2, 64);
            p += __shfl_xor(p, 4, 64);
            p += __shfl_xor(p, 8, 64);
            if (sub == 0) out[e[q]] = p + bias2;
        }
    }
}

extern "C" void kernel_launch(void* const* d_in, const int* in_sizes, int n_in,
                              void* d_out, int out_size, void* d_ws, size_t ws_size,
                              hipStream_t stream) {
    const float* z  = (const float*)d_in[0];
    const int*   ei = (const int*)d_in[1];   // [2, N_EDGES] int32
    const float* W1 = (const float*)d_in[2];
    const float* b1 = (const float*)d_in[3];
    const float* W2 = (const float*)d_in[4];
    const float* b2 = (const float*)d_in[5];
    float* out = (float*)d_out;

    __bf16* w1f  = (__bf16*)d_ws;                          // 64 KB
    __bf16* Cbuf = (__bf16*)((char*)d_ws + 65536);         // 51.2 MB

    cvt_w1f_kernel<<<16, 256, 0, stream>>>(W1, w1f);
    node_gemm_kernel<<<(N_NODES + 255) / 256, 256, 0, stream>>>(z, w1f, Cbuf);
    edge_kernel<<<1024, 256, 0, stream>>>(Cbuf, ei, b1, W2, b2, out);
}

// Round 8
// 151.071 us; speedup vs baseline: 1.0651x; 1.0651x over previous
//
#include <hip/hip_runtime.h>
#include <hip/hip_bf16.h>

#define N_NODES 100000
#define N_EDGES 500000

using bf16x8 = __attribute__((ext_vector_type(8))) __bf16;
using f32x4  = __attribute__((ext_vector_type(4))) float;

// ws layout: [0,64KB) w1f = W' [128,256] bf16, MFMA B-fragment order;
//            [64KB, +51.2MB) C = [N_NODES][256] bf16, PERMUTED per 128-col half:
//            C[r][h*128 + (c&15)*8 + (c>>4)] = (z[r] @ W'_h)[c]
// h = relu(src@W1a + dst@W1b + b1); W' = [W1a | W1b]

// ---- kernel 1: W1 f32 -> W' bf16 fragment-ordered ----
// frag = kq*16 + c16 ; lane holds W'[k = kq*32+(l>>4)*8+i][n = c16*16+(l&15)]
__global__ void cvt_w1f_kernel(const float* __restrict__ W1, __bf16* __restrict__ w1f) {
    int t = blockIdx.x * 256 + threadIdx.x;  // 0..4095
    int lane = t & 63, frag = t >> 6;
    int kq = frag >> 4, c16 = frag & 15;
    int k0 = kq * 32 + (lane >> 4) * 8;
    int n  = c16 * 16 + (lane & 15);
    bf16x8 o;
#pragma unroll
    for (int i = 0; i < 8; i++) {
        int k = k0 + i;
        float w = (n < 128) ? W1[k * 128 + n] : W1[(k + 128) * 128 + (n - 128)];
        o[i] = (__bf16)w;
    }
    ((bf16x8*)w1f)[t] = o;
}

// ---- kernel 2: node GEMM, 16 rows/wave, 64 rows/block, no LDS ----
// grid = 1563 blocks -> 6252 waves (~24/CU available); VGPR ~100 -> 16 waves/CU cap.
__global__ __launch_bounds__(256, 4) void node_gemm_kernel(
    const float* __restrict__ z, const __bf16* __restrict__ w1f,
    __bf16* __restrict__ C)
{
    const int lane = threadIdx.x & 63;
    const int wave = threadIdx.x >> 6;
    const int l15 = lane & 15, l4 = lane >> 4;
    const int r0 = blockIdx.x * 64 + wave * 16;

    // ---- load + convert A: 4 frags (kq), 16 VGPRs as bf16 ----
    int r = r0 + l15;
    if (r >= N_NODES) r = N_NODES - 1;            // tail clamp, store predicated
    const float* arow = z + (size_t)r * 128 + l4 * 8;
    bf16x8 afr[4];
#pragma unroll
    for (int kq = 0; kq < 4; kq++) {
        const float4* p = (const float4*)(arow + kq * 32);
        float4 x0 = p[0], x1 = p[1];
        bf16x8 a;
        a[0] = (__bf16)x0.x; a[1] = (__bf16)x0.y; a[2] = (__bf16)x0.z; a[3] = (__bf16)x0.w;
        a[4] = (__bf16)x1.x; a[5] = (__bf16)x1.y; a[6] = (__bf16)x1.z; a[7] = (__bf16)x1.w;
        afr[kq] = a;
    }

    const f32x4 zero = {0.f, 0.f, 0.f, 0.f};

#pragma unroll
    for (int h = 0; h < 2; h++) {
        f32x4 acc[8];
#pragma unroll
        for (int nt = 0; nt < 8; nt++) acc[nt] = zero;

#pragma unroll
        for (int kq = 0; kq < 4; kq++) {
            bf16x8 bfr[8];
#pragma unroll
            for (int nt = 0; nt < 8; nt++)
                bfr[nt] = *(const bf16x8*)(w1f + ((kq * 16 + h * 8 + nt) * 64 + lane) * 8);
#pragma unroll
            for (int nt = 0; nt < 8; nt++)
                acc[nt] = __builtin_amdgcn_mfma_f32_16x16x32_bf16(afr[kq], bfr[nt], acc[nt], 0, 0, 0);
        }

        // permuted store: C[rr*256 + h*128 + l15*8 + nt] = acc[nt][j]
#pragma unroll
        for (int j = 0; j < 4; j++) {
            int rr = r0 + l4 * 4 + j;
            if (rr < N_NODES) {
                bf16x8 o;
#pragma unroll
                for (int nt = 0; nt < 8; nt++) o[nt] = (__bf16)acc[nt][j];
                *(bf16x8*)(C + (size_t)rr * 256 + h * 128 + l15 * 8) = o;
            }
        }
    }
}

// ---- kernel 3: edge gather + fused epilogue (permuted-channel aware) ----
// lane = g*16 + sub ; 8 quads = 32 edges per wave-iter (16 gathers in flight)
__global__ __launch_bounds__(256, 4) void edge_kernel(
    const __bf16* __restrict__ C, const int* __restrict__ ei,
    const float* __restrict__ b1, const float* __restrict__ W2,
    const float* __restrict__ b2, float* __restrict__ out)
{
    const int lane = threadIdx.x & 63;
    const int wave = threadIdx.x >> 6;
    const int g = lane >> 4, sub = lane & 15;

    float b1v[8], w2v[8];
#pragma unroll
    for (int i = 0; i < 8; i++) {
        b1v[i] = b1[i * 16 + sub];
        w2v[i] = W2[i * 16 + sub];
    }
    const float bias2 = b2[0];

    const int wid = blockIdx.x * 4 + wave;
    const int nw  = gridDim.x * 4;

    // 32 edges per wave-iteration (8 quads); N_EDGES % 32 == 0
    for (int eb = wid * 32; eb < N_EDGES; eb += nw * 32) {
        bf16x8 cu[8], cv[8];
        int e[8];
#pragma unroll
        for (int q = 0; q < 8; q++) {
            e[q] = eb + q * 4 + g;
            int is = ei[e[q]];
            int id = ei[N_EDGES + e[q]];
            cu[q] = *(const bf16x8*)(C + (size_t)is * 256 + sub * 8);
            cv[q] = *(const bf16x8*)(C + (size_t)id * 256 + 128 + sub * 8);
        }
#pragma unroll
        for (int q = 0; q < 8; q++) {
            float p = 0.f;
#pragma unroll
            for (int i = 0; i < 8; i++) {
                float hc = (float)cu[q][i] + (float)cv[q][i] + b1v[i];
                p += fmaxf(hc, 0.f) * w2v[i];
            }
            p += __shfl_xor(p, 1, 64);
            p += __shfl_xor(p, 2, 64);
            p += __shfl_xor(p, 4, 64);
            p += __shfl_xor(p, 8, 64);
            if (sub == 0) out[e[q]] = p + bias2;
        }
    }
}

extern "C" void kernel_launch(void* const* d_in, const int* in_sizes, int n_in,
                              void* d_out, int out_size, void* d_ws, size_t ws_size,
                              hipStream_t stream) {
    const float* z  = (const float*)d_in[0];
    const int*   ei = (const int*)d_in[1];   // [2, N_EDGES] int32
    const float* W1 = (const float*)d_in[2];
    const float* b1 = (const float*)d_in[3];
    const float* W2 = (const float*)d_in[4];
    const float* b2 = (const float*)d_in[5];
    float* out = (float*)d_out;

    __bf16* w1f  = (__bf16*)d_ws;                          // 64 KB
    __bf16* Cbuf = (__bf16*)((char*)d_ws + 65536);         // 51.2 MB

    cvt_w1f_kernel<<<16, 256, 0, stream>>>(W1, w1f);
    node_gemm_kernel<<<(N_NODES + 63) / 64, 256, 0, stream>>>(z, w1f, Cbuf);
    edge_kernel<<<1024, 256, 0, stream>>>(Cbuf, ei, b1, W2, b2, out);
}